// Round 7
// baseline (434.398 us; speedup 1.0000x reference)
//
#include <hip/hip_runtime.h>
#include <hip/hip_bf16.h>
#include <stdint.h>

// Problem constants (CorrelationModule): x[8,384,48,48], O=512, N=48*48=2304
#define B_    8
#define CIN   384
#define OCH   512
#define NTOK  2304
#define SCALE 0.044194173824159216f  // 1/sqrt(512)

typedef unsigned short u16;
typedef u16   u16x8 __attribute__((ext_vector_type(8)));
typedef u16   u16x4 __attribute__((ext_vector_type(4)));
typedef short s16x8 __attribute__((ext_vector_type(8)));
typedef float f32x4 __attribute__((ext_vector_type(4)));

// ---------- bf16 helpers (bit-level, RNE) ----------
__device__ __forceinline__ float bf2f(u16 u) {
    union { uint32_t i; float f; } v; v.i = ((uint32_t)u) << 16; return v.f;
}
__device__ __forceinline__ u16 f2bf(float f) {
    union { uint32_t i; float f; } v; v.f = f;
    uint32_t r = v.i + 0x7fffu + ((v.i >> 16) & 1u);
    return (u16)(r >> 16);
}

// ---------- async global->LDS (width 16) ----------
typedef __attribute__((address_space(1))) const uint32_t glb_u32;
typedef __attribute__((address_space(3))) uint32_t lds_u32;

// =====================================================================
// ROWS x 32 bf16 tile, chunk-permuted LDS layout (ROWS*2 chunks of 16 B):
//   cidx(row, col8) = (row>>4)*64 + col8*16 + (row&15)
// Fragment read (16-row group g, lanes kq=ln>>4, lrow=ln&15) touches 64
// CONTIGUOUS chunks -> conflict-free ds_read_b128 (verified R5/R6:
// SQ_LDS_BANK_CONFLICT == 0). Staging instruction ck: lane l writes chunk
// ck*64+l = global (row ck*16 + (l&15), col (l>>4)*8); wave-uniform base.
// BK=32 / 16-row granularity keeps LDS small (m132: big tiles kill occ).
// =====================================================================
template <int ROWS>
__device__ __forceinline__ void stage_async(const u16* __restrict__ src, int ld,
                                            u16* __restrict__ dst, int t)
{
    const int lane = t & 63;
    const int w = t >> 6;
    constexpr int ITS = ROWS / 64;               // instructions per wave
#pragma unroll
    for (int it = 0; it < ITS; ++it) {
        const int ck  = w * ITS + it;            // 0 .. ROWS/16-1
        const int row = ck * 16 + (lane & 15);
        const int col = (lane >> 4) * 8;         // u16 col 0/8/16/24
        const u16* gp = src + (size_t)row * ld + col;
        u16* lp = dst + ck * 512;                // 1024 B per instruction
        __builtin_amdgcn_global_load_lds((glb_u32*)gp, (lds_u32*)lp, 16, 0, 0);
    }
}

// Wave tile = (WI*16) x (WJ*16); block = 2x2 waves = (WI*32) x (WJ*32).
// wm16/wn16 are the wave's row/col offsets in 16-unit granularity.
template <int WI, int WJ>
__device__ __forceinline__ void mfma_core_t(const u16* __restrict__ As,
                                            const u16* __restrict__ Bs,
                                            int wm16, int wn16, int lrow, int kq,
                                            f32x4 acc[WI][WJ])
{
    s16x8 a[WI], b[WJ];
#pragma unroll
    for (int i = 0; i < WI; ++i)
        a[i] = *(const s16x8*)(As + (((wm16 + i) * 64) + kq * 16 + lrow) * 8);
#pragma unroll
    for (int j = 0; j < WJ; ++j)
        b[j] = *(const s16x8*)(Bs + (((wn16 + j) * 64) + kq * 16 + lrow) * 8);
#pragma unroll
    for (int i = 0; i < WI; ++i)
#pragma unroll
        for (int j = 0; j < WJ; ++j)
            acc[i][j] = __builtin_amdgcn_mfma_f32_16x16x32_bf16(a[i], b[j], acc[i][j], 0, 0, 0);
}

// =====================================================================
// Kernel 0a: weight cast fp32 -> bf16
// =====================================================================
#define WQKV_SZ (OCH * CIN)
#define WO_SZ   (OCH * OCH)
#define WTOT    (3 * WQKV_SZ + WO_SZ)

__global__ __launch_bounds__(256) void prep_w_kernel(
    const float* __restrict__ Wq, const float* __restrict__ Wk,
    const float* __restrict__ Wv, const float* __restrict__ Wo,
    u16* __restrict__ Wqb, u16* __restrict__ Wkb,
    u16* __restrict__ Wvb, u16* __restrict__ Wob)
{
    const int i4 = (blockIdx.x * 256 + threadIdx.x) * 4;
    if (i4 >= WTOT) return;
    const float* src; u16* dst; int off;
    if      (i4 < WQKV_SZ)     { src = Wq; dst = Wqb; off = i4; }
    else if (i4 < 2 * WQKV_SZ) { src = Wk; dst = Wkb; off = i4 - WQKV_SZ; }
    else if (i4 < 3 * WQKV_SZ) { src = Wv; dst = Wvb; off = i4 - 2 * WQKV_SZ; }
    else                       { src = Wo; dst = Wob; off = i4 - 3 * WQKV_SZ; }
    float4 v = *(const float4*)(src + off);
    u16x4 o;
    o.x = f2bf(v.x); o.y = f2bf(v.y); o.z = f2bf(v.z); o.w = f2bf(v.w);
    *(u16x4*)(dst + off) = o;
}

// =====================================================================
// Kernel 0b: transpose x [B,C,N] fp32 -> xT [B,N,C] bf16.  64x64 tiles.
// =====================================================================
__global__ __launch_bounds__(256) void transpose_x_kernel(
    const float* __restrict__ x, u16* __restrict__ xT)
{
    const int n0 = blockIdx.x * 64;
    const int c0 = blockIdx.y * 64;
    const int b  = blockIdx.z;
    const float* X = x + (size_t)b * CIN * NTOK;

    __shared__ float Ts[64][66];

    const int t = threadIdx.x;
#pragma unroll
    for (int rep = 0; rep < 4; ++rep) {
        const int cr = (t >> 4) + rep * 16;
        const int n4 = (t & 15) * 4;
        float4 v = *(const float4*)(X + (size_t)(c0 + cr) * NTOK + n0 + n4);
        *(float2*)&Ts[cr][n4]     = make_float2(v.x, v.y);
        *(float2*)&Ts[cr][n4 + 2] = make_float2(v.z, v.w);
    }
    __syncthreads();

    u16* O = xT + (size_t)b * NTOK * CIN;
#pragma unroll
    for (int rep = 0; rep < 2; ++rep) {
        const int nr = (t >> 3) + rep * 32;
        const int c8 = (t & 7) * 8;
        u16 tmp[8];
#pragma unroll
        for (int j = 0; j < 8; ++j) tmp[j] = f2bf(Ts[c8 + j][nr]);
        *(u16x8*)(O + (size_t)(n0 + nr) * CIN + c0 + c8) = *(const u16x8*)tmp;
    }
}

// =====================================================================
// Merged Q+K projection (128x128): z = which*8 + batch (batch <-> XCD).
// =====================================================================
__global__ __launch_bounds__(256) void qk_kernel(
    const u16* __restrict__ xT,
    const u16* __restrict__ Wqb, const float* __restrict__ bq,
    const u16* __restrict__ Wkb, const float* __restrict__ bk,
    u16* __restrict__ Qt, u16* __restrict__ Kt)
{
    const int zz  = blockIdx.x % 16;
    const int b   = zz & 7, which = zz >> 3;
    const int rem = blockIdx.x / 16;
    const int n0 = (rem % 4) * 128;
    const int m0 = (rem / 4) * 128;
    const u16* A  = xT + (size_t)b * NTOK * CIN + (size_t)m0 * CIN;
    const u16* Bp = (which ? Wkb : Wqb) + (size_t)n0 * CIN;
    const float* bias = which ? bk : bq;
    u16* C = (which ? Kt : Qt) + (size_t)b * NTOK * OCH;

    __shared__ u16 As[128 * 32];
    __shared__ u16 Bs[128 * 32];

    const int t = threadIdx.x;
    const int w = t >> 6, ln = t & 63;
    const int wm16 = (w & 1) * 4, wn16 = (w >> 1) * 4;
    const int lrow = ln & 15, kq = ln >> 4;

    f32x4 acc[4][4] = {};

    for (int k0 = 0; k0 < CIN; k0 += 32) {
        stage_async<128>(A + k0, CIN, As, t);
        stage_async<128>(Bp + k0, CIN, Bs, t);
        __syncthreads();
        mfma_core_t<4, 4>(As, Bs, wm16, wn16, lrow, kq, acc);
        __syncthreads();
    }

#pragma unroll
    for (int i = 0; i < 4; ++i) {
        const int row = m0 + (wm16 + i) * 16 + kq * 4;
#pragma unroll
        for (int r = 0; r < 4; ++r)
#pragma unroll
            for (int j = 0; j < 4; ++j) {
                const int col = n0 + (wn16 + j) * 16 + lrow;
                C[(size_t)(row + r) * OCH + col] = f2bf(acc[i][j][r] + bias[col]);
            }
    }
}

// =====================================================================
// Generic MFMA GEMM, tile (WI*32)x(WJ*32): C[m][n]=sum_k A[m][k]*B[n][k]
// BIAS: 0 none, 1 row, 2 col.  1-D grid: z = bid % GZ, n0 fast.
// =====================================================================
template <int BIAS, int WI, int WJ, typename OutT>
__global__ __launch_bounds__(256) void gemm_kernel(
    const u16* __restrict__ Ag, const u16* __restrict__ Bg,
    const float* __restrict__ bias, OutT* __restrict__ Cg,
    int K, int N, long sA, long sB, long sC, int GX, int GZ)
{
    constexpr int BM = WI * 32, BN = WJ * 32;
    const int z   = blockIdx.x % GZ;
    const int rem = blockIdx.x / GZ;
    const int n0 = (rem % GX) * BN;
    const int m0 = (rem / GX) * BM;
    const u16* A  = Ag + (size_t)z * sA + (size_t)m0 * K;
    const u16* Bp = Bg + (size_t)z * sB + (size_t)n0 * K;
    OutT* C = Cg + (size_t)z * sC;

    __shared__ u16 As[BM * 32];
    __shared__ u16 Bs[BN * 32];

    const int t = threadIdx.x;
    const int w = t >> 6, ln = t & 63;
    const int wm16 = (w & 1) * WI, wn16 = (w >> 1) * WJ;
    const int lrow = ln & 15, kq = ln >> 4;

    f32x4 acc[WI][WJ] = {};

    for (int k0 = 0; k0 < K; k0 += 32) {
        stage_async<BM>(A + k0, K, As, t);
        stage_async<BN>(Bp + k0, K, Bs, t);
        __syncthreads();
        mfma_core_t<WI, WJ>(As, Bs, wm16, wn16, lrow, kq, acc);
        __syncthreads();
    }

#pragma unroll
    for (int i = 0; i < WI; ++i) {
        const int row = m0 + (wm16 + i) * 16 + kq * 4;
#pragma unroll
        for (int r = 0; r < 4; ++r) {
            float badd = 0.f;
            if (BIAS == 1) badd = bias[row + r];
#pragma unroll
            for (int j = 0; j < WJ; ++j) {
                const int col = n0 + (wn16 + j) * 16 + lrow;
                float v = acc[i][j][r];
                if (BIAS == 1) v += badd;
                if (BIAS == 2) v += bias[col];
                if constexpr (sizeof(OutT) == 2)
                    C[(size_t)(row + r) * N + col] = f2bf(v);
                else
                    C[(size_t)(row + r) * N + col] = v;
            }
        }
    }
}

// =====================================================================
// Logits+exp kernel (128x128): E[n][m] = exp(SCALE * Qt[n]. Kt[m]);
// rowsumG[z][n] += partial row sums (fp32, device atomics).
// =====================================================================
__global__ __launch_bounds__(256) void logits_exp_kernel(
    const u16* __restrict__ Qt, const u16* __restrict__ Kt,
    u16* __restrict__ Ew, float* __restrict__ rowsumG)
{
    const int z   = blockIdx.x % B_;
    const int rem = blockIdx.x / B_;
    const int n0 = (rem % (NTOK / 128)) * 128;
    const int m0 = (rem / (NTOK / 128)) * 128;
    const u16* A  = Qt + (size_t)z * NTOK * OCH + (size_t)m0 * OCH;
    const u16* Bp = Kt + (size_t)z * NTOK * OCH + (size_t)n0 * OCH;

    __shared__ u16 As[128 * 32];
    __shared__ u16 Bs[128 * 32];
    __shared__ float rowsumL[128];

    const int t = threadIdx.x;
    const int w = t >> 6, ln = t & 63;
    const int wm16 = (w & 1) * 4, wn16 = (w >> 1) * 4;
    const int lrow = ln & 15, kq = ln >> 4;

    if (t < 128) rowsumL[t] = 0.f;

    f32x4 acc[4][4] = {};

    for (int k0 = 0; k0 < OCH; k0 += 32) {
        stage_async<128>(A + k0, OCH, As, t);
        stage_async<128>(Bp + k0, OCH, Bs, t);
        __syncthreads();
        mfma_core_t<4, 4>(As, Bs, wm16, wn16, lrow, kq, acc);
        __syncthreads();
    }

    u16* E = Ew + (size_t)z * NTOK * NTOK;
#pragma unroll
    for (int i = 0; i < 4; ++i) {
        const int row = m0 + (wm16 + i) * 16 + kq * 4;
#pragma unroll
        for (int r = 0; r < 4; ++r) {
            float part = 0.f;
#pragma unroll
            for (int j = 0; j < 4; ++j) {
                const int col = n0 + (wn16 + j) * 16 + lrow;
                float e = __expf(acc[i][j][r] * SCALE);
                part += e;
                E[(size_t)(row + r) * NTOK + col] = f2bf(e);
            }
            part += __shfl_xor(part, 1);
            part += __shfl_xor(part, 2);
            part += __shfl_xor(part, 4);
            part += __shfl_xor(part, 8);
            if (lrow == 0) atomicAdd(&rowsumL[(wm16 + i) * 16 + kq * 4 + r], part);
        }
    }
    __syncthreads();
    if (t < 128) atomicAdd(&rowsumG[(size_t)z * NTOK + m0 + t], rowsumL[t]);
}

// =====================================================================
// PV kernel (128x64 tile -> 1152 blocks):
//   AOt[n][o] = (sum_m E[n][m] * V[o][m]) / rowsumG[z][n]
// =====================================================================
__global__ __launch_bounds__(256) void pv_div_kernel(
    const u16* __restrict__ Ew, const u16* __restrict__ Vw,
    const float* __restrict__ rowsumG, u16* __restrict__ AOt)
{
    const int z   = blockIdx.x % B_;
    const int rem = blockIdx.x / B_;
    const int n0 = (rem % 8) * 64;               // o-cols (64-wide), fast
    const int m0 = (rem / 8) * 128;              // token rows
    const u16* A  = Ew + (size_t)z * NTOK * NTOK + (size_t)m0 * NTOK;
    const u16* Bp = Vw + (size_t)z * OCH * NTOK + (size_t)n0 * NTOK;

    __shared__ u16 As[128 * 32];
    __shared__ u16 Bs[64 * 32];

    const int t = threadIdx.x;
    const int w = t >> 6, ln = t & 63;
    const int wm16 = (w & 1) * 4, wn16 = (w >> 1) * 2;
    const int lrow = ln & 15, kq = ln >> 4;

    f32x4 acc[4][2] = {};

    for (int k0 = 0; k0 < NTOK; k0 += 32) {
        stage_async<128>(A + k0, NTOK, As, t);
        stage_async<64>(Bp + k0, NTOK, Bs, t);
        __syncthreads();
        mfma_core_t<4, 2>(As, Bs, wm16, wn16, lrow, kq, acc);
        __syncthreads();
    }

    u16* AO = AOt + (size_t)z * NTOK * OCH;
#pragma unroll
    for (int i = 0; i < 4; ++i) {
        const int row = m0 + (wm16 + i) * 16 + kq * 4;
#pragma unroll
        for (int r = 0; r < 4; ++r) {
            const float inv = 1.0f / rowsumG[(size_t)z * NTOK + row + r];
#pragma unroll
            for (int j = 0; j < 2; ++j) {
                const int col = n0 + (wn16 + j) * 16 + lrow;
                AO[(size_t)(row + r) * OCH + col] = f2bf(acc[i][j][r] * inv);
            }
        }
    }
}

// =====================================================================
extern "C" void kernel_launch(void* const* d_in, const int* in_sizes, int n_in,
                              void* d_out, int out_size, void* d_ws, size_t ws_size,
                              hipStream_t stream)
{
    const float* x  = (const float*)d_in[0];
    const float* Wq = (const float*)d_in[1];
    const float* bq = (const float*)d_in[2];
    const float* Wk = (const float*)d_in[3];
    const float* bk = (const float*)d_in[4];
    const float* Wv = (const float*)d_in[5];
    const float* bv = (const float*)d_in[6];
    const float* Wo = (const float*)d_in[7];
    const float* bo = (const float*)d_in[8];
    float* out = (float*)d_out;

    u16* ws = (u16*)d_ws;
    u16* Wqb = ws;
    u16* Wkb = Wqb + WQKV_SZ;
    u16* Wvb = Wkb + WQKV_SZ;
    u16* Wob = Wvb + WQKV_SZ;
    u16* xT  = Wob + WO_SZ;
    const size_t xtsz  = (size_t)B_ * NTOK * CIN;
    const size_t qkvsz = (size_t)B_ * NTOK * OCH;
    u16* Qt  = xT + xtsz;
    u16* Kt  = Qt + qkvsz;
    u16* Vw  = Kt + qkvsz;
    u16* Ew  = Vw + qkvsz;                          // B*N*N
    float* rowsumG = (float*)(Ew + (size_t)B_ * NTOK * NTOK);
    u16* AOt = Qt;                                  // alias: Qt dead after logits
    // total approx 157.5 MB

    dim3 blk(256);

    prep_w_kernel<<<dim3((WTOT / 4 + 255) / 256), blk, 0, stream>>>(
        Wq, Wk, Wv, Wo, Wqb, Wkb, Wvb, Wob);
    transpose_x_kernel<<<dim3(NTOK / 64, CIN / 64, B_), blk, 0, stream>>>(x, xT);
    hipMemsetAsync(rowsumG, 0, (size_t)B_ * NTOK * sizeof(float), stream);

    // Q & K merged: 4 o-tiles x 18 token-tiles x 16 (which*8+batch) = 1152
    qk_kernel<<<dim3(4 * 18 * 16), blk, 0, stream>>>(
        xT, Wqb, bq, Wkb, bk, Qt, Kt);
    // V[o][m] = Wv[o].xT[m] + bv[o]: 64x128 tiles -> 18*8*8 = 1152 blocks
    gemm_kernel<1, 2, 4, u16><<<dim3(18 * 8 * B_), blk, 0, stream>>>(
        Wvb, xT, bv, Vw, CIN, NTOK, 0L, (long)NTOK * CIN, (long)OCH * NTOK, 18, B_);

    // E = exp(scale * Qt.Kt^T), rowsumG += row sums  (18x18x8 = 2592)
    logits_exp_kernel<<<dim3(18 * 18 * B_), blk, 0, stream>>>(Qt, Kt, Ew, rowsumG);

    // AOt = (E.V^T) / rowsum: 128x64 tiles -> 8*18*8 = 1152 blocks
    pv_div_kernel<<<dim3(8 * 18 * B_), blk, 0, stream>>>(Ew, Vw, rowsumG, AOt);

    // out[p][n] = Wo[p].AOt[n] + bo[p]: 64x128 tiles -> 18*8*8 = 1152 blocks
    gemm_kernel<1, 2, 4, float><<<dim3(18 * 8 * B_), blk, 0, stream>>>(
        Wob, AOt, bo, out, OCH, NTOK, 0L, (long)NTOK * OCH, (long)OCH * NTOK, 18, B_);
}

// Round 8
// 305.007 us; speedup vs baseline: 1.4242x; 1.4242x over previous
//
#include <hip/hip_runtime.h>
#include <hip/hip_bf16.h>
#include <stdint.h>

// Problem constants (CorrelationModule): x[8,384,48,48], O=512, N=48*48=2304
#define B_    8
#define CIN   384
#define OCH   512
#define NTOK  2304
#define SCALE 0.044194173824159216f  // 1/sqrt(512)

typedef unsigned short u16;
typedef u16   u16x8 __attribute__((ext_vector_type(8)));
typedef short s16x8 __attribute__((ext_vector_type(8)));
typedef float f32x4 __attribute__((ext_vector_type(4)));

// ---------- bf16 helpers (bit-level, RNE) ----------
__device__ __forceinline__ float bf2f(u16 u) {
    union { uint32_t i; float f; } v; v.i = ((uint32_t)u) << 16; return v.f;
}
__device__ __forceinline__ u16 f2bf(float f) {
    union { uint32_t i; float f; } v; v.f = f;
    uint32_t r = v.i + 0x7fffu + ((v.i >> 16) & 1u);
    return (u16)(r >> 16);
}

// ---------- async global->LDS (width 16) ----------
typedef __attribute__((address_space(1))) const uint32_t glb_u32;
typedef __attribute__((address_space(3))) uint32_t lds_u32;

// =====================================================================
// BRICK FORMAT for all bf16 intermediates.
// Tensor [M][K] (16|M, 32|K) = array of 1-KB bricks: brick (g, c) covers
// rows g*16..+16, cols c*32..+32, at u16 offset ((g*(K/32)+c)*512).
// Inside a brick: chunk l (l=0..63, 16 B each) = (col8 = l>>4, row = l&15),
// holding 8 consecutive u16 of one row.  u16 offset of (row, col):
//   ((col>>3)&3)*128 + (row&15)*8 + (col&7)
// WHY: one global_load_lds instruction reads chunk l at lane l ->
// 1 KB FULLY CONTIGUOUS global read (R5/R6's row-scattered staging did 64
// scattered 16-B reads -> 4x the VMEM transactions; that was the R4->R6
// regression).  LDS image = same chunk order as R5/R6 -> fragment
// ds_read_b128 hits 64 consecutive chunks: SQ_LDS_BANK_CONFLICT == 0
// (verified R6/R7).
// =====================================================================
__device__ __forceinline__ size_t baddr(int row, int col, int Kc) {
    return ((size_t)(row >> 4) * (Kc >> 5) + (col >> 5)) * 512
         + (size_t)(((col >> 3) & 3) * 128 + (row & 15) * 8 + (col & 7));
}

// stage a 128x32 brick-format tile (rows row0..+128, cols k0..+32) into LDS
__device__ __forceinline__ void stage_blocked(const u16* __restrict__ base,
                                              int row0, int k0, int Kc,
                                              u16* __restrict__ dst, int t)
{
    const int lane = t & 63;
    const int w = t >> 6;
    const int bpr = Kc >> 5;
#pragma unroll
    for (int it = 0; it < 2; ++it) {
        const int ck = w * 2 + it;               // 0..7 (16-row groups)
        const u16* gp = base + ((size_t)((row0 >> 4) + ck) * bpr + (k0 >> 5)) * 512
                      + (size_t)lane * 8;
        u16* lp = dst + ck * 512;                // wave-uniform base
        __builtin_amdgcn_global_load_lds((glb_u32*)gp, (lds_u32*)lp, 16, 0, 0);
    }
}

// 2x2-wave 128x128 MFMA core (16 MFMA/wave per BK=32 step; proven R6/R7)
__device__ __forceinline__ void mfma_core(const u16* __restrict__ As,
                                          const u16* __restrict__ Bs,
                                          int wm16, int wn16, int lrow, int kq,
                                          f32x4 acc[4][4])
{
    s16x8 a[4], b[4];
#pragma unroll
    for (int i = 0; i < 4; ++i)
        a[i] = *(const s16x8*)(As + (((wm16 + i) * 64) + kq * 16 + lrow) * 8);
#pragma unroll
    for (int j = 0; j < 4; ++j)
        b[j] = *(const s16x8*)(Bs + (((wn16 + j) * 64) + kq * 16 + lrow) * 8);
#pragma unroll
    for (int i = 0; i < 4; ++i)
#pragma unroll
        for (int j = 0; j < 4; ++j)
            acc[i][j] = __builtin_amdgcn_mfma_f32_16x16x32_bf16(a[i], b[j], acc[i][j], 0, 0, 0);
}

// =====================================================================
// Kernel 0a: weight cast fp32 -> bf16, BRICK output.
// One thread = one 16-B chunk: contiguous u16x8 write, 32-B src reads.
// =====================================================================
#define WQKV_SZ (OCH * CIN)
#define WO_SZ   (OCH * OCH)
#define CH_QKV  (WQKV_SZ / 8)     // 24576 chunks per qkv weight
#define CH_WO   (WO_SZ / 8)       // 32768
#define CH_TOT  (3 * CH_QKV + CH_WO)

__global__ __launch_bounds__(256) void prep_w_kernel(
    const float* __restrict__ Wq, const float* __restrict__ Wk,
    const float* __restrict__ Wv, const float* __restrict__ Wo,
    u16* __restrict__ Wqb, u16* __restrict__ Wkb,
    u16* __restrict__ Wvb, u16* __restrict__ Wob)
{
    int lc = blockIdx.x * 256 + threadIdx.x;
    if (lc >= CH_TOT) return;
    const float* src; u16* dst; int Kc;
    if      (lc < CH_QKV)     { src = Wq; dst = Wqb; Kc = CIN; }
    else if (lc < 2 * CH_QKV) { src = Wk; dst = Wkb; Kc = CIN; lc -= CH_QKV; }
    else if (lc < 3 * CH_QKV) { src = Wv; dst = Wvb; Kc = CIN; lc -= 2 * CH_QKV; }
    else                      { src = Wo; dst = Wob; Kc = OCH; lc -= 3 * CH_QKV; }
    const int brick = lc >> 6, l = lc & 63;
    const int bpr = Kc >> 5;
    const int g = brick / bpr, c = brick % bpr;
    const int row = g * 16 + (l & 15);
    const int col = c * 32 + (l >> 4) * 8;
    const float* s = src + (size_t)row * Kc + col;
    float4 v0 = *(const float4*)s;
    float4 v1 = *(const float4*)(s + 4);
    u16x8 o;
    o[0] = f2bf(v0.x); o[1] = f2bf(v0.y); o[2] = f2bf(v0.z); o[3] = f2bf(v0.w);
    o[4] = f2bf(v1.x); o[5] = f2bf(v1.y); o[6] = f2bf(v1.z); o[7] = f2bf(v1.w);
    *(u16x8*)(dst + (size_t)lc * 8) = o;
}

// =====================================================================
// Kernel 0b: transpose x [B,C,N] fp32 -> xT [B,N,C] bf16 BRICK.
// =====================================================================
__global__ __launch_bounds__(256) void transpose_x_kernel(
    const float* __restrict__ x, u16* __restrict__ xT)
{
    const int n0 = blockIdx.x * 64;
    const int c0 = blockIdx.y * 64;
    const int b  = blockIdx.z;
    const float* X = x + (size_t)b * CIN * NTOK;

    __shared__ float Ts[64][66];

    const int t = threadIdx.x;
#pragma unroll
    for (int rep = 0; rep < 4; ++rep) {
        const int cr = (t >> 4) + rep * 16;
        const int n4 = (t & 15) * 4;
        float4 v = *(const float4*)(X + (size_t)(c0 + cr) * NTOK + n0 + n4);
        *(float2*)&Ts[cr][n4]     = make_float2(v.x, v.y);
        *(float2*)&Ts[cr][n4 + 2] = make_float2(v.z, v.w);
    }
    __syncthreads();

    u16* O = xT + (size_t)b * NTOK * CIN;
#pragma unroll
    for (int rep = 0; rep < 2; ++rep) {
        const int nr = (t >> 3) + rep * 32;
        const int c8 = (t & 7) * 8;
        u16 tmp[8];
#pragma unroll
        for (int j = 0; j < 8; ++j) tmp[j] = f2bf(Ts[c8 + j][nr]);
        *(u16x8*)(O + baddr(n0 + nr, c0 + c8, CIN)) = *(const u16x8*)tmp;
    }
}

// =====================================================================
// Merged Q+K projection (128x128, brick in/out): z = which*8 + batch.
// =====================================================================
__global__ __launch_bounds__(256) void qk_kernel(
    const u16* __restrict__ xT,
    const u16* __restrict__ Wqb, const float* __restrict__ bq,
    const u16* __restrict__ Wkb, const float* __restrict__ bk,
    u16* __restrict__ Qt, u16* __restrict__ Kt)
{
    const int zz  = blockIdx.x % 16;
    const int b   = zz & 7, which = zz >> 3;
    const int rem = blockIdx.x / 16;
    const int n0 = (rem % 4) * 128;
    const int m0 = (rem / 4) * 128;
    const u16* A  = xT + (size_t)b * NTOK * CIN;
    const u16* Bp = which ? Wkb : Wqb;
    const float* bias = which ? bk : bq;
    u16* C = (which ? Kt : Qt) + (size_t)b * NTOK * OCH;

    __shared__ u16 As[128 * 32];
    __shared__ u16 Bs[128 * 32];

    const int t = threadIdx.x;
    const int w = t >> 6, ln = t & 63;
    const int wm16 = (w & 1) * 4, wn16 = (w >> 1) * 4;
    const int lrow = ln & 15, kq = ln >> 4;

    f32x4 acc[4][4] = {};

    for (int k0 = 0; k0 < CIN; k0 += 32) {
        stage_blocked(A, m0, k0, CIN, As, t);
        stage_blocked(Bp, n0, k0, CIN, Bs, t);
        __syncthreads();
        mfma_core(As, Bs, wm16, wn16, lrow, kq, acc);
        __syncthreads();
    }

#pragma unroll
    for (int i = 0; i < 4; ++i) {
        const int row = m0 + (wm16 + i) * 16 + kq * 4;
#pragma unroll
        for (int r = 0; r < 4; ++r)
#pragma unroll
            for (int j = 0; j < 4; ++j) {
                const int col = n0 + (wn16 + j) * 16 + lrow;
                C[baddr(row + r, col, OCH)] = f2bf(acc[i][j][r] + bias[col]);
            }
    }
}

// =====================================================================
// Generic MFMA GEMM (128x128, brick A/B): C[m][n] = sum_k A[m][k]*B[n][k]
// BIAS: 1 row bias.  OutT u16 -> brick C; float -> row-major C.
// 1-D grid: z = bid % GZ (batch<->XCD), n0 fast.
// =====================================================================
template <int BIAS, typename OutT>
__global__ __launch_bounds__(256) void gemm_kernel(
    const u16* __restrict__ Ag, const u16* __restrict__ Bg,
    const float* __restrict__ bias, OutT* __restrict__ Cg,
    int K, int N, long sA, long sB, long sC, int GX, int GZ)
{
    const int z   = blockIdx.x % GZ;
    const int rem = blockIdx.x / GZ;
    const int n0 = (rem % GX) * 128;
    const int m0 = (rem / GX) * 128;
    const u16* A  = Ag + (size_t)z * sA;
    const u16* Bp = Bg + (size_t)z * sB;
    OutT* C = Cg + (size_t)z * sC;

    __shared__ u16 As[128 * 32];
    __shared__ u16 Bs[128 * 32];

    const int t = threadIdx.x;
    const int w = t >> 6, ln = t & 63;
    const int wm16 = (w & 1) * 4, wn16 = (w >> 1) * 4;
    const int lrow = ln & 15, kq = ln >> 4;

    f32x4 acc[4][4] = {};

    for (int k0 = 0; k0 < K; k0 += 32) {
        stage_blocked(A, m0, k0, K, As, t);
        stage_blocked(Bp, n0, k0, K, Bs, t);
        __syncthreads();
        mfma_core(As, Bs, wm16, wn16, lrow, kq, acc);
        __syncthreads();
    }

#pragma unroll
    for (int i = 0; i < 4; ++i) {
        const int row = m0 + (wm16 + i) * 16 + kq * 4;
#pragma unroll
        for (int r = 0; r < 4; ++r) {
            float badd = 0.f;
            if (BIAS == 1) badd = bias[row + r];
#pragma unroll
            for (int j = 0; j < 4; ++j) {
                const int col = n0 + (wn16 + j) * 16 + lrow;
                float v = acc[i][j][r] + badd;
                if constexpr (sizeof(OutT) == 2)
                    C[baddr(row + r, col, N)] = f2bf(v);
                else
                    C[(size_t)(row + r) * N + col] = v;
            }
        }
    }
}

// =====================================================================
// Logits+exp kernel (128x128, brick): E[n][m] = exp(SCALE * Qt[n].Kt[m]);
// rowsumG[z][n] += partial row sums (fp32 device atomics).
// =====================================================================
__global__ __launch_bounds__(256) void logits_exp_kernel(
    const u16* __restrict__ Qt, const u16* __restrict__ Kt,
    u16* __restrict__ Ew, float* __restrict__ rowsumG)
{
    const int z   = blockIdx.x % B_;
    const int rem = blockIdx.x / B_;
    const int n0 = (rem % (NTOK / 128)) * 128;   // Kt token tiles, fast
    const int m0 = (rem / (NTOK / 128)) * 128;   // Qt token tiles
    const u16* A  = Qt + (size_t)z * NTOK * OCH;
    const u16* Bp = Kt + (size_t)z * NTOK * OCH;

    __shared__ u16 As[128 * 32];
    __shared__ u16 Bs[128 * 32];
    __shared__ float rowsumL[128];

    const int t = threadIdx.x;
    const int w = t >> 6, ln = t & 63;
    const int wm16 = (w & 1) * 4, wn16 = (w >> 1) * 4;
    const int lrow = ln & 15, kq = ln >> 4;

    if (t < 128) rowsumL[t] = 0.f;

    f32x4 acc[4][4] = {};

    for (int k0 = 0; k0 < OCH; k0 += 32) {
        stage_blocked(A, m0, k0, OCH, As, t);
        stage_blocked(Bp, n0, k0, OCH, Bs, t);
        __syncthreads();
        mfma_core(As, Bs, wm16, wn16, lrow, kq, acc);
        __syncthreads();
    }

    u16* E = Ew + (size_t)z * NTOK * NTOK;
#pragma unroll
    for (int i = 0; i < 4; ++i) {
        const int row = m0 + (wm16 + i) * 16 + kq * 4;
#pragma unroll
        for (int r = 0; r < 4; ++r) {
            float part = 0.f;
#pragma unroll
            for (int j = 0; j < 4; ++j) {
                const int col = n0 + (wn16 + j) * 16 + lrow;
                float e = __expf(acc[i][j][r] * SCALE);
                part += e;
                E[baddr(row + r, col, NTOK)] = f2bf(e);
            }
            part += __shfl_xor(part, 1);
            part += __shfl_xor(part, 2);
            part += __shfl_xor(part, 4);
            part += __shfl_xor(part, 8);
            if (lrow == 0) atomicAdd(&rowsumL[(wm16 + i) * 16 + kq * 4 + r], part);
        }
    }
    __syncthreads();
    if (t < 128) atomicAdd(&rowsumG[(size_t)z * NTOK + m0 + t], rowsumL[t]);
}

// =====================================================================
// PV kernel (128x128, brick): AOt[n][o] = (sum_m E[n][m]*V[o][m]) / rowsum
// =====================================================================
__global__ __launch_bounds__(256) void pv_div_kernel(
    const u16* __restrict__ Ew, const u16* __restrict__ Vw,
    const float* __restrict__ rowsumG, u16* __restrict__ AOt)
{
    const int z   = blockIdx.x % B_;
    const int rem = blockIdx.x / B_;
    const int n0 = (rem % 4) * 128;              // o tiles, fast
    const int m0 = (rem / 4) * 128;              // token tiles
    const u16* A  = Ew + (size_t)z * NTOK * NTOK;
    const u16* Bp = Vw + (size_t)z * OCH * NTOK;

    __shared__ u16 As[128 * 32];
    __shared__ u16 Bs[128 * 32];

    const int t = threadIdx.x;
    const int w = t >> 6, ln = t & 63;
    const int wm16 = (w & 1) * 4, wn16 = (w >> 1) * 4;
    const int lrow = ln & 15, kq = ln >> 4;

    f32x4 acc[4][4] = {};

    for (int k0 = 0; k0 < NTOK; k0 += 32) {
        stage_blocked(A, m0, k0, NTOK, As, t);
        stage_blocked(Bp, n0, k0, NTOK, Bs, t);
        __syncthreads();
        mfma_core(As, Bs, wm16, wn16, lrow, kq, acc);
        __syncthreads();
    }

    u16* AO = AOt + (size_t)z * NTOK * OCH;
#pragma unroll
    for (int i = 0; i < 4; ++i) {
        const int row = m0 + (wm16 + i) * 16 + kq * 4;
#pragma unroll
        for (int r = 0; r < 4; ++r) {
            const float inv = 1.0f / rowsumG[(size_t)z * NTOK + row + r];
#pragma unroll
            for (int j = 0; j < 4; ++j) {
                const int col = n0 + (wn16 + j) * 16 + lrow;
                AO[baddr(row + r, col, OCH)] = f2bf(acc[i][j][r] * inv);
            }
        }
    }
}

// =====================================================================
extern "C" void kernel_launch(void* const* d_in, const int* in_sizes, int n_in,
                              void* d_out, int out_size, void* d_ws, size_t ws_size,
                              hipStream_t stream)
{
    const float* x  = (const float*)d_in[0];
    const float* Wq = (const float*)d_in[1];
    const float* bq = (const float*)d_in[2];
    const float* Wk = (const float*)d_in[3];
    const float* bk = (const float*)d_in[4];
    const float* Wv = (const float*)d_in[5];
    const float* bv = (const float*)d_in[6];
    const float* Wo = (const float*)d_in[7];
    const float* bo = (const float*)d_in[8];
    float* out = (float*)d_out;

    u16* ws = (u16*)d_ws;
    u16* Wqb = ws;
    u16* Wkb = Wqb + WQKV_SZ;
    u16* Wvb = Wkb + WQKV_SZ;
    u16* Wob = Wvb + WQKV_SZ;
    u16* xT  = Wob + WO_SZ;
    const size_t xtsz  = (size_t)B_ * NTOK * CIN;
    const size_t qkvsz = (size_t)B_ * NTOK * OCH;
    u16* Qt  = xT + xtsz;
    u16* Kt  = Qt + qkvsz;
    u16* Vw  = Kt + qkvsz;
    u16* Ew  = Vw + qkvsz;                          // B*N*N
    float* rowsumG = (float*)(Ew + (size_t)B_ * NTOK * NTOK);
    u16* AOt = Qt;                                  // alias: Qt dead after logits
    // total approx 157.5 MB

    dim3 blk(256);

    prep_w_kernel<<<dim3((CH_TOT + 255) / 256), blk, 0, stream>>>(
        Wq, Wk, Wv, Wo, Wqb, Wkb, Wvb, Wob);
    transpose_x_kernel<<<dim3(NTOK / 64, CIN / 64, B_), blk, 0, stream>>>(x, xT);
    hipMemsetAsync(rowsumG, 0, (size_t)B_ * NTOK * sizeof(float), stream);

    // Q & K merged: 4 o-tiles x 18 token-tiles x 16 (which*8+batch) = 1152
    qk_kernel<<<dim3(4 * 18 * 16), blk, 0, stream>>>(
        xT, Wqb, bq, Wkb, bk, Qt, Kt);
    // V[o][m] = Wv[o].xT[m] + bv[o]: 18 n-tiles (fast) x 4 m-tiles x 8 = 576
    gemm_kernel<1, u16><<<dim3(18 * 4 * B_), blk, 0, stream>>>(
        Wvb, xT, bv, Vw, CIN, NTOK, 0L, (long)NTOK * CIN, (long)OCH * NTOK, 18, B_);

    // E = exp(scale * Qt.Kt^T), rowsumG += row sums  (18x18x8 = 2592)
    logits_exp_kernel<<<dim3(18 * 18 * B_), blk, 0, stream>>>(Qt, Kt, Ew, rowsumG);

    // AOt = (E.V^T) / rowsum: 4 o-tiles (fast) x 18 token-tiles x 8 = 576
    pv_div_kernel<<<dim3(4 * 18 * B_), blk, 0, stream>>>(Ew, Vw, rowsumG, AOt);

    // out[p][n] = Wo[p].AOt[n] + bo[p]: 18 n-tiles (fast) x 4 p-tiles x 8 = 576
    gemm_kernel<1, float><<<dim3(18 * 4 * B_), blk, 0, stream>>>(
        Wob, AOt, bo, out, OCH, NTOK, 0L, (long)NTOK * OCH, (long)OCH * NTOK, 18, B_);
}